// Round 6
// baseline (317.066 us; speedup 1.0000x reference)
//
#include <hip/hip_runtime.h>

#define NCLS 10
#define NUM_IMG 65536

// R6: barrier-free main loop + G=2 images per lane.
//  - Block = 448 threads (7 waves), 128 images/block, grid = 512 blocks.
//  - W staged once into LDS (31 KB), read via same-address broadcast
//    ds_read_b128; each read now feeds TWO images (16 FMAs) -> W LDS
//    traffic per image halved vs R5.
//  - x read directly per lane (global_load_dwordx4); NO main-loop barriers,
//    full unroll lets the compiler hoist independent loads for latency
//    hiding (R4 showed the scatter pattern itself is not the wall).
//  - Wave w handles patch-cols 2w,2w+1 (chunks w, w+7 of each row-pair).
__global__ __launch_bounds__(448, 4) void quanv_logits_kernel(
    const float* __restrict__ x,    // (B,1,28,28)
    const float* __restrict__ W,    // (10, 784)
    const float* __restrict__ bias, // (10,)
    float* __restrict__ out)        // (B, 10)
{
    __shared__ float sW[7840];          // W row-major 10x784 (31360 B)
    __shared__ float part[128 * 71];    // per-wave partial logits (36352 B)

    const int tid  = threadIdx.x;
    const int w    = __builtin_amdgcn_readfirstlane(tid >> 6); // 0..6 uniform
    const int lane = tid & 63;
    const int img0 = blockIdx.x << 7;   // 128 images per block

    // Stage W into LDS (coalesced), once per block.
    {
        const float4* Wg = reinterpret_cast<const float4*>(W);
        float4* Wl = reinterpret_cast<float4*>(sW);
#pragma unroll
        for (int r = 0; r < 5; ++r) {
            const int idx = tid + r * 448;
            if (idx < 1960) Wl[idx] = Wg[idx];
        }
    }

    // Two images per lane.
    const float* pA = x + (size_t)(img0 + lane) * 784;
    const float* pB = x + (size_t)(img0 + 64 + lane) * 784;

    float accA[NCLS], accB[NCLS];
#pragma unroll
    for (int c = 0; c < NCLS; ++c) { accA[c] = 0.0f; accB[c] = 0.0f; }

    __syncthreads();   // publish sW; the ONLY barrier before the epilogue

#pragma unroll
    for (int rr = 0; rr < 14; ++rr) {
        // chunk w = top-row cols 4w..4w+3 ; chunk w+7 = bottom-row same cols
        const int offT = rr * 56 + w * 4;
        const int offB = rr * 56 + (w + 7) * 4;
        const float4 tA = *reinterpret_cast<const float4*>(pA + offT);
        const float4 bA = *reinterpret_cast<const float4*>(pA + offB);
        const float4 tB = *reinterpret_cast<const float4*>(pB + offT);
        const float4 bB = *reinterpret_cast<const float4*>(pB + offB);

        // image A: patches j=2w (e*), j=2w+1 (f*)
        const float eA0 = __cosf(tA.x);
        const float eA1 = eA0 * __cosf(tA.y);
        const float eA2 = eA1 * __cosf(bA.x);
        const float eA3 = eA2 * __cosf(bA.y);
        const float fA0 = __cosf(tA.z);
        const float fA1 = fA0 * __cosf(tA.w);
        const float fA2 = fA1 * __cosf(bA.z);
        const float fA3 = fA2 * __cosf(bA.w);
        // image B
        const float eB0 = __cosf(tB.x);
        const float eB1 = eB0 * __cosf(tB.y);
        const float eB2 = eB1 * __cosf(bB.x);
        const float eB3 = eB2 * __cosf(bB.y);
        const float fB0 = __cosf(tB.z);
        const float fB1 = fB0 * __cosf(tB.w);
        const float fB2 = fB1 * __cosf(bB.z);
        const float fB3 = fB2 * __cosf(bB.w);

        const int P = (rr * 14 + 2 * w) * 4;  // wave-uniform -> broadcast
#pragma unroll
        for (int c = 0; c < NCLS; ++c) {
            const float4 wa = *reinterpret_cast<const float4*>(&sW[c * 784 + P]);
            const float4 wb = *reinterpret_cast<const float4*>(&sW[c * 784 + P + 4]);
            float a = accA[c];
            a = fmaf(eA0, wa.x, a); a = fmaf(eA1, wa.y, a);
            a = fmaf(eA2, wa.z, a); a = fmaf(eA3, wa.w, a);
            a = fmaf(fA0, wb.x, a); a = fmaf(fA1, wb.y, a);
            a = fmaf(fA2, wb.z, a); a = fmaf(fA3, wb.w, a);
            accA[c] = a;
            float b2 = accB[c];
            b2 = fmaf(eB0, wa.x, b2); b2 = fmaf(eB1, wa.y, b2);
            b2 = fmaf(eB2, wa.z, b2); b2 = fmaf(eB3, wa.w, b2);
            b2 = fmaf(fB0, wb.x, b2); b2 = fmaf(fB1, wb.y, b2);
            b2 = fmaf(fB2, wb.z, b2); b2 = fmaf(fB3, wb.w, b2);
            accB[c] = b2;
        }
    }

    // Deposit partials: image iL in [0,128), stride 71 floats (odd).
#pragma unroll
    for (int c = 0; c < NCLS; ++c) {
        part[lane * 71 + w * NCLS + c]         = accA[c];
        part[(64 + lane) * 71 + w * NCLS + c]  = accB[c];
    }
    __syncthreads();

    // Waves 0 and 1 reduce + softmax + store (wave w -> images w*64+lane).
    if (w < 2) {
        const int iL = (w << 6) + lane;
        float s[NCLS];
#pragma unroll
        for (int c = 0; c < NCLS; ++c) s[c] = bias[c];
        for (int ww = 0; ww < 7; ++ww) {
#pragma unroll
            for (int c = 0; c < NCLS; ++c) s[c] += part[iL * 71 + ww * NCLS + c];
        }
        float m = s[0];
#pragma unroll
        for (int c = 1; c < NCLS; ++c) m = fmaxf(m, s[c]);
        float sum = 0.0f;
#pragma unroll
        for (int c = 0; c < NCLS; ++c) sum += __expf(s[c] - m);
        const float lse = __logf(sum) + m;

        float* o = out + (size_t)(img0 + iL) * NCLS;
#pragma unroll
        for (int c = 0; c < NCLS; c += 2) {
            float2 v;
            v.x = s[c]     - lse;
            v.y = s[c + 1] - lse;
            *reinterpret_cast<float2*>(o + c) = v;
        }
    }
}

extern "C" void kernel_launch(void* const* d_in, const int* in_sizes, int n_in,
                              void* d_out, int out_size, void* d_ws, size_t ws_size,
                              hipStream_t stream) {
    const float* x    = (const float*)d_in[0];
    const float* W    = (const float*)d_in[1];
    const float* bias = (const float*)d_in[2];
    float* out        = (float*)d_out;

    dim3 block(448);                // 7 waves
    dim3 grid(NUM_IMG / 128);       // 512 blocks, 128 images each
    quanv_logits_kernel<<<grid, block, 0, stream>>>(x, W, bias, out);
}

// Round 7
// 291.003 us; speedup vs baseline: 1.0896x; 1.0896x over previous
//
#include <hip/hip_runtime.h>
#include <hip/hip_bf16.h>

#define NCLS 10
#define NUM_IMG 65536

typedef __attribute__((ext_vector_type(8))) short short8;  // 8 bf16 (4 VGPRs)
typedef __attribute__((ext_vector_type(4))) float f32x4;   // 4 fp32 acc

union FragAB { short8 v; unsigned int u[4]; };

__device__ __forceinline__ unsigned int pack_bf16(float a, float b) {
    union { __hip_bfloat162 h; unsigned int u; } cv;
    cv.h = __float22bfloat162_rn(make_float2(a, b));   // a -> low, b -> high
    return cv.u;
}

// R7: MFMA formulation. C(16 img x 16 cls) += A(16x32 feat) * B(32x16 W^T).
// Block = 256 threads (4 waves), 64 images; wave wv owns images wv*16..+15.
// K order (conceptual): step (rr, h) covers patches rr*14 + 8h .. +7 (h=1 has
// only 6 valid patches; the 2 invalid get ZERO B-frags so A can be garbage).
// Lane (q=lane>>4, m=lane&15): A-frag = 2 patches (2q,2q+1 of the step) of
// image m = one (t4,b4) float4 pair -> 8-deep cumprod chain, packed bf16.
// B-frags pre-packed once per block into LDS with the SAME (q,j) slot map,
// so the hardware's physical K-permutation cancels out.
// W sharing now happens inside the matrix unit: 1 KB B-frag read per 8192
// MACs (16x less W-LDS traffic than R5). No main-loop barriers.
__global__ __launch_bounds__(256, 4) void quanv_mfma_kernel(
    const float* __restrict__ x,    // (B,1,28,28)
    const float* __restrict__ W,    // (10, 784)
    const float* __restrict__ bias, // (10,)
    float* __restrict__ out)        // (B, 10)
{
    __shared__ unsigned int sWB[28 * 64 * 4];  // 28 K-steps x 64 lanes x 16 B = 28672 B
    __shared__ float part[4 * 16 * 18];        // per-wave [16 img][18] logits, 4608 B

    const int tid  = threadIdx.x;
    const int wv   = tid >> 6;       // 0..3
    const int lane = tid & 63;
    const int q    = lane >> 4;      // lane-group 0..3
    const int sub  = lane & 15;      // m for A / n for B / cls in C
    const int img0 = blockIdx.x << 6;

    // ---- Pack W into B-fragment layout (bf16), once per block ----
    // Frag f = step*64 + slot; slot (qB, n): element j holds
    // W[n][p*4 + (j&3)] with p = rr*14 + 8h + 2qB + (j>>2); zero if invalid.
    for (int f = tid; f < 28 * 64; f += 256) {
        const int step = f >> 6, sl = f & 63;
        const int qB = sl >> 4, n = sl & 15;
        const int rr = step >> 1, h = step & 1;
        unsigned int u0 = 0, u1 = 0, u2 = 0, u3 = 0;
        if (n < NCLS) {
            const int pr0 = 8 * h + 2 * qB;       // patch-in-row for j<4
            if (pr0 < 14) {
                const float* wp = W + n * 784 + (rr * 14 + pr0) * 4;
                u0 = pack_bf16(wp[0], wp[1]);
                u1 = pack_bf16(wp[2], wp[3]);
            }
            if (pr0 + 1 < 14) {
                const float* wp = W + n * 784 + (rr * 14 + pr0 + 1) * 4;
                u2 = pack_bf16(wp[0], wp[1]);
                u3 = pack_bf16(wp[2], wp[3]);
            }
        }
        *reinterpret_cast<uint4*>(&sWB[f * 4]) = make_uint4(u0, u1, u2, u3);
    }
    __syncthreads();   // publish sWB — the only pre-epilogue barrier

    // ---- Main loop: 14 row-pairs x 2 MFMA steps, barrier-free ----
    const float* __restrict__ img = x + (size_t)(img0 + wv * 16 + sub) * 784;
    f32x4 acc = {0.f, 0.f, 0.f, 0.f};

#pragma unroll
    for (int rr = 0; rr < 14; ++rr) {
        // ---- step h=0: patches rr*14 + {0..7}; lane q -> patches 2q,2q+1
        {
            const float4 t4 = *reinterpret_cast<const float4*>(img + rr * 56 + q * 4);
            const float4 b4 = *reinterpret_cast<const float4*>(img + rr * 56 + 28 + q * 4);
            const float e0 = __cosf(t4.x);
            const float e1 = e0 * __cosf(t4.y);
            const float e2 = e1 * __cosf(b4.x);
            const float e3 = e2 * __cosf(b4.y);
            const float f0 = __cosf(t4.z);
            const float f1 = f0 * __cosf(t4.w);
            const float f2 = f1 * __cosf(b4.z);
            const float f3 = f2 * __cosf(b4.w);
            FragAB a;
            a.u[0] = pack_bf16(e0, e1); a.u[1] = pack_bf16(e2, e3);
            a.u[2] = pack_bf16(f0, f1); a.u[3] = pack_bf16(f2, f3);
            FragAB bfr;
            *reinterpret_cast<uint4*>(bfr.u) =
                *reinterpret_cast<const uint4*>(&sWB[((rr * 2) * 64 + lane) * 4]);
            acc = __builtin_amdgcn_mfma_f32_16x16x32_bf16(a.v, bfr.v, acc, 0, 0, 0);
        }
        // ---- step h=1: patches rr*14 + {8..13}; q=3 invalid (B=0 there)
        {
            float4 t4 = {0.f, 0.f, 0.f, 0.f}, b4 = {0.f, 0.f, 0.f, 0.f};
            if (q < 3) {   // keep loads in-bounds; q=3 frag is multiplied by zero B
                t4 = *reinterpret_cast<const float4*>(img + rr * 56 + 16 + q * 4);
                b4 = *reinterpret_cast<const float4*>(img + rr * 56 + 44 + q * 4);
            }
            const float e0 = __cosf(t4.x);
            const float e1 = e0 * __cosf(t4.y);
            const float e2 = e1 * __cosf(b4.x);
            const float e3 = e2 * __cosf(b4.y);
            const float f0 = __cosf(t4.z);
            const float f1 = f0 * __cosf(t4.w);
            const float f2 = f1 * __cosf(b4.z);
            const float f3 = f2 * __cosf(b4.w);
            FragAB a;
            a.u[0] = pack_bf16(e0, e1); a.u[1] = pack_bf16(e2, e3);
            a.u[2] = pack_bf16(f0, f1); a.u[3] = pack_bf16(f2, f3);
            FragAB bfr;
            *reinterpret_cast<uint4*>(bfr.u) =
                *reinterpret_cast<const uint4*>(&sWB[((rr * 2 + 1) * 64 + lane) * 4]);
            acc = __builtin_amdgcn_mfma_f32_16x16x32_bf16(a.v, bfr.v, acc, 0, 0, 0);
        }
    }

    // ---- Epilogue: C/D layout col(cls)=lane&15, row(img)=q*4+reg ----
    float* pw = part + wv * (16 * 18);
    if (sub < NCLS) {
        const float bn = bias[sub];
#pragma unroll
        for (int r = 0; r < 4; ++r)
            pw[(q * 4 + r) * 18 + sub] = acc[r] + bn;
    }
    __syncthreads();

    if (lane < 16) {
        const float* row = pw + lane * 18;
        float s[NCLS];
#pragma unroll
        for (int c = 0; c < NCLS; ++c) s[c] = row[c];
        float m = s[0];
#pragma unroll
        for (int c = 1; c < NCLS; ++c) m = fmaxf(m, s[c]);
        float sum = 0.0f;
#pragma unroll
        for (int c = 0; c < NCLS; ++c) sum += __expf(s[c] - m);
        const float lse = __logf(sum) + m;

        float* o = out + (size_t)(img0 + wv * 16 + lane) * NCLS;
#pragma unroll
        for (int c = 0; c < NCLS; c += 2) {
            float2 v;
            v.x = s[c]     - lse;
            v.y = s[c + 1] - lse;
            *reinterpret_cast<float2*>(o + c) = v;   // 8-aligned (40 B stride)
        }
    }
}

extern "C" void kernel_launch(void* const* d_in, const int* in_sizes, int n_in,
                              void* d_out, int out_size, void* d_ws, size_t ws_size,
                              hipStream_t stream) {
    const float* x    = (const float*)d_in[0];
    const float* W    = (const float*)d_in[1];
    const float* bias = (const float*)d_in[2];
    float* out        = (float*)d_out;

    dim3 block(256);               // 4 waves, 64 images
    dim3 grid(NUM_IMG / 64);       // 1024 blocks
    quanv_mfma_kernel<<<grid, block, 0, stream>>>(x, W, bias, out);
}